// Round 4
// baseline (246.740 us; speedup 1.0000x reference)
//
#include <hip/hip_runtime.h>

// Mamba-2 SSD chunked scan, 3-phase MFMA decomposition (round 4).
// Round-4 changes: kA/kC process 2 chunks per block with register prefetch of
// chunk1 globals overlapping chunk0 MFMA phases (de-correlates load bursts);
// 4x4 in-register transpose staging for X^T/B^T (4 vector LDS writes vs 16
// scalar); kC stores Y directly from registers (no sY LDS staging/barrier).

typedef __bf16 bf16x4 __attribute__((ext_vector_type(4)));
typedef __bf16 bf16x8 __attribute__((ext_vector_type(8)));
typedef float  f32x4  __attribute__((ext_vector_type(4)));

constexpr int LDT = 72;   // padded LDS row stride (bf16), 144 B (16B-aligned rows)

__device__ __forceinline__ f32x4 mfma16(bf16x8 a, bf16x8 b, f32x4 c) {
    return __builtin_amdgcn_mfma_f32_16x16x32_bf16(a, b, c, 0, 0, 0);
}

// ---------------- Phase A: chunk states (2 chunks/block) ----------------
__global__ __launch_bounds__(256, 4)
void kA_chunkstate(const float* __restrict__ Xg, const float* __restrict__ Ag,
                   const float* __restrict__ Bg, __bf16* __restrict__ states,
                   float* __restrict__ cs63)
{
    const int cp = blockIdx.x, hh = blockIdx.y, bb = blockIdx.z;
    const int tid = threadIdx.x;
    __shared__ __bf16 sXt[64][LDT];   // X^T scaled [p][l]  (later: out staging [p][n])
    __shared__ __bf16 sBt[64][LDT];   // B^T [n][l]
    __shared__ float  sds[2][64];
    const int c0 = cp * 2;
    const size_t base0 = (size_t)bb*4096 + (size_t)c0*64;

    // ---- both chunks' A-scans in parallel (waves 0,1) ----
    if (tid < 128) {
        const int w = tid >> 6, ln = tid & 63;
        float v = Ag[(base0 + w*64 + ln)*16 + hh];
        #pragma unroll
        for (int o = 1; o < 64; o <<= 1) { float u = __shfl_up(v, o, 64); if (ln >= o) v += u; }
        const float last = __shfl(v, 63, 64);
        sds[w][ln] = expf(last - v);
        if (ln == 63) cs63[((size_t)bb*16 + hh)*64 + c0 + w] = v;
    }

    // ---- issue ALL global loads (both chunks) upfront ----
    const int lt0 = (tid >> 4) * 4;   // l block
    const int cq0 = (tid & 15) * 4;   // p/n col block
    float xr[2][4][4], br[2][4][4];
    #pragma unroll
    for (int k = 0; k < 2; ++k)
        #pragma unroll
        for (int j = 0; j < 4; ++j) {
            const size_t go = ((base0 + k*64 + lt0 + j)*16 + hh)*(size_t)64 + cq0;
            *reinterpret_cast<float4*>(xr[k][j]) = *reinterpret_cast<const float4*>(&Xg[go]);
            *reinterpret_cast<float4*>(br[k][j]) = *reinterpret_cast<const float4*>(&Bg[go]);
        }

    const int lane = tid & 63;
    const int wm = ((tid >> 7) & 1) * 32;
    const int wn = ((tid >> 6) & 1) * 32;
    const int fr = lane & 15, fg = lane >> 4;

    __syncthreads();   // S0: sds published

    #pragma unroll
    for (int k = 0; k < 2; ++k) {
        // ---- stage (4x4 reg transpose, vector LDS writes) ----
        const float d0 = sds[k][lt0], d1 = sds[k][lt0+1];
        const float d2 = sds[k][lt0+2], d3 = sds[k][lt0+3];
        #pragma unroll
        for (int q = 0; q < 4; ++q) {
            *reinterpret_cast<bf16x4*>(&sBt[cq0+q][lt0]) =
                (bf16x4){(__bf16)br[k][0][q], (__bf16)br[k][1][q],
                         (__bf16)br[k][2][q], (__bf16)br[k][3][q]};
            *reinterpret_cast<bf16x4*>(&sXt[cq0+q][lt0]) =
                (bf16x4){(__bf16)(xr[k][0][q]*d0), (__bf16)(xr[k][1][q]*d1),
                         (__bf16)(xr[k][2][q]*d2), (__bf16)(xr[k][3][q]*d3)};
        }
        __syncthreads();  // S1: stage visible

        f32x4 acc[2][2] = {};
        #pragma unroll
        for (int ks = 0; ks < 2; ++ks) {
            const int k0 = ks*32 + fg*8;
            const bf16x8 a0 = *reinterpret_cast<const bf16x8*>(&sXt[wm      + fr][k0]);
            const bf16x8 a1 = *reinterpret_cast<const bf16x8*>(&sXt[wm + 16 + fr][k0]);
            const bf16x8 b0 = *reinterpret_cast<const bf16x8*>(&sBt[wn      + fr][k0]);
            const bf16x8 b1 = *reinterpret_cast<const bf16x8*>(&sBt[wn + 16 + fr][k0]);
            acc[0][0] = mfma16(a0, b0, acc[0][0]);
            acc[0][1] = mfma16(a0, b1, acc[0][1]);
            acc[1][0] = mfma16(a1, b0, acc[1][0]);
            acc[1][1] = mfma16(a1, b1, acc[1][1]);
        }
        __syncthreads();  // S2: LDS reads done; overlay sXt with output

        __bf16 (*sOut)[LDT] = sXt;
        #pragma unroll
        for (int mt = 0; mt < 2; ++mt)
            #pragma unroll
            for (int nt = 0; nt < 2; ++nt)
                #pragma unroll
                for (int r = 0; r < 4; ++r)
                    sOut[wm + 16*mt + fg*4 + r][wn + 16*nt + fr] = (__bf16)acc[mt][nt][r];
        __syncthreads();  // S3: sOut visible

        __bf16* dst = states + (((size_t)bb*16 + hh)*64 + c0 + k)*(size_t)4096;
        #pragma unroll
        for (int it = 0; it < 2; ++it) {
            const int flat = tid + 256*it;
            const int p = flat >> 3, n8 = (flat & 7)*8;
            *reinterpret_cast<bf16x8*>(&dst[p*64 + n8]) =
                *reinterpret_cast<const bf16x8*>(&sOut[p][n8]);
        }
        if (k == 0) __syncthreads();  // S4: sOut reads done before restage
    }
}

// ---------------- Phase B: prefix scan over chunks (in-place) ----------------
__global__ __launch_bounds__(256)
void kB_scan(const float* __restrict__ Ig, __bf16* __restrict__ states,
             const float* __restrict__ cs63)
{
    const int ph = blockIdx.x, hh = blockIdx.y, bb = blockIdx.z;
    const int tid = threadIdx.x;
    const int p  = ph*32 + (tid >> 3);
    const int n8 = (tid & 7) * 8;
    const float* ip = &Ig[(((size_t)bb*16 + hh)*64 + p)*(size_t)64 + n8];
    const float4 i0 = *reinterpret_cast<const float4*>(ip);
    const float4 i1 = *reinterpret_cast<const float4*>(ip + 4);
    float r[8] = {i0.x, i0.y, i0.z, i0.w, i1.x, i1.y, i1.z, i1.w};
    const float* csp = &cs63[((size_t)bb*16 + hh)*64];
    __bf16* sp = states + ((size_t)bb*16 + hh)*64*4096 + p*64 + n8;

    bf16x8 nxt = *reinterpret_cast<const bf16x8*>(sp);
    float dnxt = expf(csp[0]);
    for (int c = 0; c < 64; ++c) {
        const bf16x8 cur = nxt;
        const float d = dnxt;
        if (c < 63) {
            nxt = *reinterpret_cast<const bf16x8*>(sp + (size_t)(c + 1)*4096);
            dnxt = expf(csp[c + 1]);
        }
        bf16x8 pr;
        #pragma unroll
        for (int j = 0; j < 8; ++j) pr[j] = (__bf16)r[j];
        *reinterpret_cast<bf16x8*>(sp + (size_t)c*4096) = pr;   // prefix[c]
        #pragma unroll
        for (int j = 0; j < 8; ++j) r[j] = fmaf(d, r[j], (float)cur[j]);
    }
}

// ---------------- Phase C: outputs (2 chunks/block, direct Y stores) ----------
struct SMemC {
    __bf16 Ct[64][LDT];   // C row-major [l][n]
    __bf16 Sp[64][LDT];   // prefix state [p][n]
    __bf16 BM[64][LDT];   // B row-major [l][n], then overlaid by M [i][j]
    __bf16 Xt[64][LDT];   // X^T [p][l]
    float  dout[2][64];
    float  din[2][64];
};

__global__ __launch_bounds__(256, 4)
void kC_output(const float* __restrict__ Xg, const float* __restrict__ Ag,
               const float* __restrict__ Bg, const float* __restrict__ Cg,
               const __bf16* __restrict__ states, float* __restrict__ Yg)
{
    const int cp = blockIdx.x, hh = blockIdx.y, bb = blockIdx.z;
    const int tid = threadIdx.x;
    __shared__ __align__(16) SMemC sm;
    const int c0 = cp * 2;
    const size_t base0 = (size_t)bb*4096 + (size_t)c0*64;

    // ---- both chunks' A-scans (waves 0,1) ----
    if (tid < 128) {
        const int w = tid >> 6, ln = tid & 63;
        float v = Ag[(base0 + w*64 + ln)*16 + hh];
        #pragma unroll
        for (int o = 1; o < 64; o <<= 1) { float u = __shfl_up(v, o, 64); if (ln >= o) v += u; }
        sm.dout[w][ln] = expf(v);
        sm.din[w][ln]  = expf(-v);
    }

    // flat map (C/B): rows r0+16*it, col group c4 ; 4x4 map (X): rows lt0+j, col cq0
    const int r0  = tid >> 4,      c4  = (tid & 15) * 4;
    const int lt0 = (tid >> 4)*4,  cq0 = (tid & 15) * 4;
    const int p0s = tid >> 3,      n8s = (tid & 7) * 8;

    // ---- chunk0 + both states upfront ----
    float cv[2][4][4], bv[2][4][4], xr[2][4][4];
    bf16x8 st[2][2];
    const __bf16* stp = states + ((((size_t)bb*16 + hh)*64 + c0) << 12);
    #pragma unroll
    for (int k = 0; k < 2; ++k) {
        st[k][0] = *reinterpret_cast<const bf16x8*>(&stp[(size_t)k*4096 + p0s*64 + n8s]);
        st[k][1] = *reinterpret_cast<const bf16x8*>(&stp[(size_t)k*4096 + (p0s + 32)*64 + n8s]);
    }
    #pragma unroll
    for (int it = 0; it < 4; ++it) {
        const size_t go = ((base0 + r0 + 16*it)*16 + hh)*(size_t)64 + c4;
        *reinterpret_cast<float4*>(cv[0][it]) = *reinterpret_cast<const float4*>(&Cg[go]);
        *reinterpret_cast<float4*>(bv[0][it]) = *reinterpret_cast<const float4*>(&Bg[go]);
    }
    #pragma unroll
    for (int j = 0; j < 4; ++j) {
        const size_t go = ((base0 + lt0 + j)*16 + hh)*(size_t)64 + cq0;
        *reinterpret_cast<float4*>(xr[0][j]) = *reinterpret_cast<const float4*>(&Xg[go]);
    }

    const int lane = tid & 63;
    const int wm = ((tid >> 7) & 1) * 32;
    const int wn = ((tid >> 6) & 1) * 32;
    const int fr = lane & 15, fg = lane >> 4;

    #pragma unroll
    for (int k = 0; k < 2; ++k) {
        // ---- stage chunk k ----
        #pragma unroll
        for (int it = 0; it < 4; ++it) {
            const int l = r0 + 16*it;
            *reinterpret_cast<bf16x4*>(&sm.Ct[l][c4]) =
                (bf16x4){(__bf16)cv[k][it][0], (__bf16)cv[k][it][1],
                         (__bf16)cv[k][it][2], (__bf16)cv[k][it][3]};
            *reinterpret_cast<bf16x4*>(&sm.BM[l][c4]) =
                (bf16x4){(__bf16)bv[k][it][0], (__bf16)bv[k][it][1],
                         (__bf16)bv[k][it][2], (__bf16)bv[k][it][3]};
        }
        #pragma unroll
        for (int q = 0; q < 4; ++q)
            *reinterpret_cast<bf16x4*>(&sm.Xt[cq0+q][lt0]) =
                (bf16x4){(__bf16)xr[k][0][q], (__bf16)xr[k][1][q],
                         (__bf16)xr[k][2][q], (__bf16)xr[k][3][q]};
        *reinterpret_cast<bf16x8*>(&sm.Sp[p0s][n8s])      = st[k][0];
        *reinterpret_cast<bf16x8*>(&sm.Sp[p0s + 32][n8s]) = st[k][1];
        __syncthreads();   // S1: stage visible (k=0: scan also covered)

        // ---- prefetch chunk1 globals during chunk0 compute ----
        if (k == 0) {
            #pragma unroll
            for (int it = 0; it < 4; ++it) {
                const size_t go = ((base0 + 64 + r0 + 16*it)*16 + hh)*(size_t)64 + c4;
                *reinterpret_cast<float4*>(cv[1][it]) = *reinterpret_cast<const float4*>(&Cg[go]);
                *reinterpret_cast<float4*>(bv[1][it]) = *reinterpret_cast<const float4*>(&Bg[go]);
            }
            #pragma unroll
            for (int j = 0; j < 4; ++j) {
                const size_t go = ((base0 + 64 + lt0 + j)*16 + hh)*(size_t)64 + cq0;
                *reinterpret_cast<float4*>(xr[1][j]) = *reinterpret_cast<const float4*>(&Xg[go]);
            }
        }

        // ---- phase 1: G = C B^T  and  ao = C @ Sp^T ----
        f32x4 g[2][2] = {}, ao[2][2] = {};
        #pragma unroll
        for (int ks = 0; ks < 2; ++ks) {
            const int k0 = ks*32 + fg*8;
            const bf16x8 a0 = *reinterpret_cast<const bf16x8*>(&sm.Ct[wm      + fr][k0]);
            const bf16x8 a1 = *reinterpret_cast<const bf16x8*>(&sm.Ct[wm + 16 + fr][k0]);
            const bf16x8 b0 = *reinterpret_cast<const bf16x8*>(&sm.BM[wn      + fr][k0]);
            const bf16x8 b1 = *reinterpret_cast<const bf16x8*>(&sm.BM[wn + 16 + fr][k0]);
            g[0][0] = mfma16(a0, b0, g[0][0]);
            g[0][1] = mfma16(a0, b1, g[0][1]);
            g[1][0] = mfma16(a1, b0, g[1][0]);
            g[1][1] = mfma16(a1, b1, g[1][1]);
            const bf16x8 s0 = *reinterpret_cast<const bf16x8*>(&sm.Sp[wn      + fr][k0]);
            const bf16x8 s1 = *reinterpret_cast<const bf16x8*>(&sm.Sp[wn + 16 + fr][k0]);
            ao[0][0] = mfma16(a0, s0, ao[0][0]);
            ao[0][1] = mfma16(a0, s1, ao[0][1]);
            ao[1][0] = mfma16(a1, s0, ao[1][0]);
            ao[1][1] = mfma16(a1, s1, ao[1][1]);
        }
        __syncthreads();   // S2: all B reads done

        // ---- M (masked decay) overlaid onto BM ----
        #pragma unroll
        for (int mt = 0; mt < 2; ++mt)
            #pragma unroll
            for (int nt = 0; nt < 2; ++nt) {
                const int j = wn + 16*nt + fr;
                const float dj = sm.din[k][j];
                #pragma unroll
                for (int r = 0; r < 4; ++r) {
                    const int i = wm + 16*mt + fg*4 + r;
                    const float val = (i >= j) ? g[mt][nt][r] * sm.dout[k][i] * dj : 0.0f;
                    sm.BM[i][j] = (__bf16)val;
                }
            }
        __syncthreads();   // S3: M fully written

        // ---- phase 2: ad = M @ X ; Y = ad + dout[i]*ao, direct stores ----
        f32x4 ad[2][2] = {};
        #pragma unroll
        for (int ks = 0; ks < 2; ++ks) {
            const int k0 = ks*32 + fg*8;
            const bf16x8 m0 = *reinterpret_cast<const bf16x8*>(&sm.BM[wm      + fr][k0]);
            const bf16x8 m1 = *reinterpret_cast<const bf16x8*>(&sm.BM[wm + 16 + fr][k0]);
            const bf16x8 x0 = *reinterpret_cast<const bf16x8*>(&sm.Xt[wn      + fr][k0]);
            const bf16x8 x1 = *reinterpret_cast<const bf16x8*>(&sm.Xt[wn + 16 + fr][k0]);
            ad[0][0] = mfma16(m0, x0, ad[0][0]);
            ad[0][1] = mfma16(m0, x1, ad[0][1]);
            ad[1][0] = mfma16(m1, x0, ad[1][0]);
            ad[1][1] = mfma16(m1, x1, ad[1][1]);
        }
        #pragma unroll
        for (int mt = 0; mt < 2; ++mt)
            #pragma unroll
            for (int r = 0; r < 4; ++r) {
                const int i = wm + 16*mt + fg*4 + r;
                const float ei = sm.dout[k][i];
                const size_t yb = ((base0 + k*64 + i)*16 + hh)*(size_t)64;
                #pragma unroll
                for (int nt = 0; nt < 2; ++nt)
                    Yg[yb + wn + 16*nt + fr] = ad[mt][nt][r] + ei*ao[mt][nt][r];
            }
        if (k == 0) __syncthreads();   // S4: phase-2 LDS reads done before restage
    }
}

extern "C" void kernel_launch(void* const* d_in, const int* in_sizes, int n_in,
                              void* d_out, int out_size, void* d_ws, size_t ws_size,
                              hipStream_t stream) {
    const float* X  = (const float*)d_in[0];
    const float* I  = (const float*)d_in[1];
    const float* A  = (const float*)d_in[2];
    const float* Bp = (const float*)d_in[3];
    const float* Cp = (const float*)d_in[4];
    float* Y = (float*)d_out;
    __bf16* states = (__bf16*)d_ws;                                   // 67,108,864 B
    float*  cs63   = (float*)((char*)d_ws + (size_t)67108864);        // 32,768 B

    kA_chunkstate<<<dim3(32,16,8), 256, 0, stream>>>(X, A, Bp, states, cs63);
    kB_scan      <<<dim3(2,16,8),  256, 0, stream>>>(I, states, cs63);
    kC_output    <<<dim3(32,16,8), 256, 0, stream>>>(X, A, Bp, Cp, states, Y);
}

// Round 5
// 224.946 us; speedup vs baseline: 1.0969x; 1.0969x over previous
//
#include <hip/hip_runtime.h>

// Mamba-2 SSD chunked scan, 3-phase MFMA decomposition (round 5).
// Phase A: chunk_state = Xs^T B (MFMA), Xs = X*exp(cs63-cs); exports Xs^T bf16
//          and cs63 for reuse by kC (removes kC's X read + transpose staging).
// Phase B: prefix scan over chunks (in-place, prefetched).
// Phase C: G=C B^T; M' = G*exp(cs_i-cs63) masked (j-independent scale!);
//          Y = M'@Xs + diag(e^{cs})*(C@prefix^T). Sp and Xs^T fragments are
//          read DIRECTLY from global bf16 (no LDS staging); M has its own LDS
//          buffer (no B-overlay barrier); sY overlays dead Ct+BM for coalesced
//          float4 stores (round-4 lesson: scalar stores -> +25% write amp).
// Grid order (hh fastest): 16 heads of one (b,chunk) share memory lines.

typedef __bf16 bf16x4 __attribute__((ext_vector_type(4)));
typedef __bf16 bf16x8 __attribute__((ext_vector_type(8)));
typedef float  f32x4  __attribute__((ext_vector_type(4)));

constexpr int LDT = 72;   // padded LDS row stride (bf16), 144 B (16B-aligned rows)

__device__ __forceinline__ f32x4 mfma16(bf16x8 a, bf16x8 b, f32x4 c) {
    return __builtin_amdgcn_mfma_f32_16x16x32_bf16(a, b, c, 0, 0, 0);
}

// ---------------- Phase A: chunk states + Xs^T export ----------------
__global__ __launch_bounds__(256, 4)
void kA_chunkstate(const float* __restrict__ Xg, const float* __restrict__ Ag,
                   const float* __restrict__ Bg, __bf16* __restrict__ states,
                   __bf16* __restrict__ xts, float* __restrict__ cs63)
{
    const int hh = blockIdx.x, cc = blockIdx.y, bb = blockIdx.z;
    const int tid = threadIdx.x;
    __shared__ __bf16 sXt[64][LDT];   // Xs^T [p][l]  (later: out staging [p][n])
    __shared__ __bf16 sBt[64][LDT];   // B^T [n][l]
    __shared__ float  sds[64];
    const size_t tbase = (size_t)bb*4096 + (size_t)cc*64;
    const size_t slab  = (((size_t)bb*16 + hh)*64 + cc)*(size_t)4096;

    // ---- issue all global loads first ----
    const int lt0 = (tid >> 4) * 4;   // l block
    const int cq0 = (tid & 15) * 4;   // p/n col block
    float xr[4][4], br[4][4];
    #pragma unroll
    for (int j = 0; j < 4; ++j) {
        const size_t go = ((tbase + lt0 + j)*16 + hh)*(size_t)64 + cq0;
        *reinterpret_cast<float4*>(xr[j]) = *reinterpret_cast<const float4*>(&Xg[go]);
        *reinterpret_cast<float4*>(br[j]) = *reinterpret_cast<const float4*>(&Bg[go]);
    }
    // ---- A scan (wave 0) ----
    if (tid < 64) {
        float v = Ag[(tbase + tid)*16 + hh];
        #pragma unroll
        for (int o = 1; o < 64; o <<= 1) { float u = __shfl_up(v, o, 64); if (tid >= o) v += u; }
        const float last = __shfl(v, 63, 64);
        sds[tid] = expf(last - v);
        if (tid == 63) cs63[((size_t)bb*16 + hh)*64 + cc] = v;
    }
    // ---- B^T stage (4x4 reg transpose, no scan dependency) ----
    #pragma unroll
    for (int q = 0; q < 4; ++q)
        *reinterpret_cast<bf16x4*>(&sBt[cq0+q][lt0]) =
            (bf16x4){(__bf16)br[0][q], (__bf16)br[1][q],
                     (__bf16)br[2][q], (__bf16)br[3][q]};
    __syncthreads();   // S0: sds ready
    const float d0 = sds[lt0], d1 = sds[lt0+1], d2 = sds[lt0+2], d3 = sds[lt0+3];
    #pragma unroll
    for (int q = 0; q < 4; ++q)
        *reinterpret_cast<bf16x4*>(&sXt[cq0+q][lt0]) =
            (bf16x4){(__bf16)(xr[0][q]*d0), (__bf16)(xr[1][q]*d1),
                     (__bf16)(xr[2][q]*d2), (__bf16)(xr[3][q]*d3)};
    __syncthreads();   // S1: stage visible

    // ---- export Xs^T (row-major [p][l], 128B rows, coalesced) ----
    __bf16* xd = xts + slab;
    #pragma unroll
    for (int it = 0; it < 2; ++it) {
        const int flat = tid + 256*it;
        const int p = flat >> 3, l8 = (flat & 7)*8;
        *reinterpret_cast<bf16x8*>(&xd[p*64 + l8]) =
            *reinterpret_cast<const bf16x8*>(&sXt[p][l8]);
    }

    const int lane = tid & 63;
    const int wm = ((tid >> 7) & 1) * 32;
    const int wn = ((tid >> 6) & 1) * 32;
    const int fr = lane & 15, fg = lane >> 4;

    f32x4 acc[2][2] = {};
    #pragma unroll
    for (int ks = 0; ks < 2; ++ks) {
        const int k0 = ks*32 + fg*8;
        const bf16x8 a0 = *reinterpret_cast<const bf16x8*>(&sXt[wm      + fr][k0]);
        const bf16x8 a1 = *reinterpret_cast<const bf16x8*>(&sXt[wm + 16 + fr][k0]);
        const bf16x8 b0 = *reinterpret_cast<const bf16x8*>(&sBt[wn      + fr][k0]);
        const bf16x8 b1 = *reinterpret_cast<const bf16x8*>(&sBt[wn + 16 + fr][k0]);
        acc[0][0] = mfma16(a0, b0, acc[0][0]);
        acc[0][1] = mfma16(a0, b1, acc[0][1]);
        acc[1][0] = mfma16(a1, b0, acc[1][0]);
        acc[1][1] = mfma16(a1, b1, acc[1][1]);
    }
    __syncthreads();  // S2: sXt reads (mfma + export) done; overlay with output

    __bf16 (*sOut)[LDT] = sXt;
    #pragma unroll
    for (int mt = 0; mt < 2; ++mt)
        #pragma unroll
        for (int nt = 0; nt < 2; ++nt)
            #pragma unroll
            for (int r = 0; r < 4; ++r)
                sOut[wm + 16*mt + fg*4 + r][wn + 16*nt + fr] = (__bf16)acc[mt][nt][r];
    __syncthreads();  // S3: sOut visible

    __bf16* dst = states + slab;
    #pragma unroll
    for (int it = 0; it < 2; ++it) {
        const int flat = tid + 256*it;
        const int p = flat >> 3, n8 = (flat & 7)*8;
        *reinterpret_cast<bf16x8*>(&dst[p*64 + n8]) =
            *reinterpret_cast<const bf16x8*>(&sOut[p][n8]);
    }
}

// ---------------- Phase B: prefix scan over chunks (in-place) ----------------
__global__ __launch_bounds__(256)
void kB_scan(const float* __restrict__ Ig, __bf16* __restrict__ states,
             const float* __restrict__ cs63)
{
    const int ph = blockIdx.x, hh = blockIdx.y, bb = blockIdx.z;
    const int tid = threadIdx.x;
    const int p  = ph*32 + (tid >> 3);
    const int n8 = (tid & 7) * 8;
    const float* ip = &Ig[(((size_t)bb*16 + hh)*64 + p)*(size_t)64 + n8];
    const float4 i0 = *reinterpret_cast<const float4*>(ip);
    const float4 i1 = *reinterpret_cast<const float4*>(ip + 4);
    float r[8] = {i0.x, i0.y, i0.z, i0.w, i1.x, i1.y, i1.z, i1.w};
    const float* csp = &cs63[((size_t)bb*16 + hh)*64];
    __bf16* sp = states + ((size_t)bb*16 + hh)*64*4096 + p*64 + n8;

    bf16x8 nxt = *reinterpret_cast<const bf16x8*>(sp);
    float dnxt = expf(csp[0]);
    for (int c = 0; c < 64; ++c) {
        const bf16x8 cur = nxt;
        const float d = dnxt;
        if (c < 63) {
            nxt = *reinterpret_cast<const bf16x8*>(sp + (size_t)(c + 1)*4096);
            dnxt = expf(csp[c + 1]);
        }
        bf16x8 pr;
        #pragma unroll
        for (int j = 0; j < 8; ++j) pr[j] = (__bf16)r[j];
        *reinterpret_cast<bf16x8*>(sp + (size_t)c*4096) = pr;   // prefix[c]
        #pragma unroll
        for (int j = 0; j < 8; ++j) r[j] = fmaf(d, r[j], (float)cur[j]);
    }
}

// ---------------- Phase C: outputs ----------------
struct SMemC {
    __bf16 Ct[64][LDT];   // C [l][n]        } overlaid by sY[64][68] f32 after
    __bf16 BM[64][LDT];   // B [l][n]        } phase-2 reads complete
    __bf16 M [64][LDT];   // masked decayed G [i][j]
    float  dout[64];      // e^{cs_i}
    float  douti[64];     // e^{cs_i - cs63}
};

__global__ __launch_bounds__(256, 5)
void kC_output(const float* __restrict__ Ag, const float* __restrict__ Bg,
               const float* __restrict__ Cg, const __bf16* __restrict__ states,
               const __bf16* __restrict__ xts, float* __restrict__ Yg)
{
    const int hh = blockIdx.x, cc = blockIdx.y, bb = blockIdx.z;
    const int tid = threadIdx.x;
    __shared__ __align__(16) SMemC sm;
    const size_t tbase = (size_t)bb*4096 + (size_t)cc*64;
    const size_t slab  = (((size_t)bb*16 + hh)*64 + cc)*(size_t)4096;

    const int r0 = tid >> 4, c4 = (tid & 15) * 4;
    const int lane = tid & 63;
    const int wm = ((tid >> 7) & 1) * 32;
    const int wn = ((tid >> 6) & 1) * 32;
    const int fr = lane & 15, fg = lane >> 4;

    // ---- issue ALL global loads upfront ----
    float cv[4][4], bv[4][4];
    #pragma unroll
    for (int it = 0; it < 4; ++it) {
        const size_t go = ((tbase + r0 + 16*it)*16 + hh)*(size_t)64 + c4;
        *reinterpret_cast<float4*>(cv[it]) = *reinterpret_cast<const float4*>(&Cg[go]);
        *reinterpret_cast<float4*>(bv[it]) = *reinterpret_cast<const float4*>(&Bg[go]);
    }
    const __bf16* stp = states + slab;
    const __bf16* xtp = xts + slab;
    bf16x8 spf[2][2], xsf[2][2];
    #pragma unroll
    for (int ks = 0; ks < 2; ++ks) {
        const int k0 = ks*32 + fg*8;
        spf[ks][0] = *reinterpret_cast<const bf16x8*>(&stp[(wn      + fr)*64 + k0]);
        spf[ks][1] = *reinterpret_cast<const bf16x8*>(&stp[(wn + 16 + fr)*64 + k0]);
        xsf[ks][0] = *reinterpret_cast<const bf16x8*>(&xtp[(wn      + fr)*64 + k0]);
        xsf[ks][1] = *reinterpret_cast<const bf16x8*>(&xtp[(wn + 16 + fr)*64 + k0]);
    }

    // ---- A scan (wave 0) -> decay tables ----
    if (tid < 64) {
        float v = Ag[(tbase + tid)*16 + hh];
        #pragma unroll
        for (int o = 1; o < 64; o <<= 1) { float u = __shfl_up(v, o, 64); if (tid >= o) v += u; }
        const float last = __shfl(v, 63, 64);
        sm.dout[tid]  = expf(v);
        sm.douti[tid] = expf(v - last);
    }

    // ---- stage C, B to LDS (bf16) ----
    #pragma unroll
    for (int it = 0; it < 4; ++it) {
        const int l = r0 + 16*it;
        *reinterpret_cast<bf16x4*>(&sm.Ct[l][c4]) =
            (bf16x4){(__bf16)cv[it][0], (__bf16)cv[it][1],
                     (__bf16)cv[it][2], (__bf16)cv[it][3]};
        *reinterpret_cast<bf16x4*>(&sm.BM[l][c4]) =
            (bf16x4){(__bf16)bv[it][0], (__bf16)bv[it][1],
                     (__bf16)bv[it][2], (__bf16)bv[it][3]};
    }
    __syncthreads();   // S1: Ct/BM/tables visible

    // ---- phase 1: G = C B^T  and  ao = C @ Sp^T (Sp frags from global) ----
    f32x4 g[2][2] = {}, ao[2][2] = {};
    #pragma unroll
    for (int ks = 0; ks < 2; ++ks) {
        const int k0 = ks*32 + fg*8;
        const bf16x8 a0 = *reinterpret_cast<const bf16x8*>(&sm.Ct[wm      + fr][k0]);
        const bf16x8 a1 = *reinterpret_cast<const bf16x8*>(&sm.Ct[wm + 16 + fr][k0]);
        const bf16x8 b0 = *reinterpret_cast<const bf16x8*>(&sm.BM[wn      + fr][k0]);
        const bf16x8 b1 = *reinterpret_cast<const bf16x8*>(&sm.BM[wn + 16 + fr][k0]);
        g[0][0] = mfma16(a0, b0, g[0][0]);
        g[0][1] = mfma16(a0, b1, g[0][1]);
        g[1][0] = mfma16(a1, b0, g[1][0]);
        g[1][1] = mfma16(a1, b1, g[1][1]);
        ao[0][0] = mfma16(a0, spf[ks][0], ao[0][0]);
        ao[0][1] = mfma16(a0, spf[ks][1], ao[0][1]);
        ao[1][0] = mfma16(a1, spf[ks][0], ao[1][0]);
        ao[1][1] = mfma16(a1, spf[ks][1], ao[1][1]);
    }

    // ---- M' = G * e^{cs_i - cs63}, masked (own buffer, no extra barrier) ----
    #pragma unroll
    for (int mt = 0; mt < 2; ++mt)
        #pragma unroll
        for (int nt = 0; nt < 2; ++nt) {
            const int j = wn + 16*nt + fr;
            #pragma unroll
            for (int r = 0; r < 4; ++r) {
                const int i = wm + 16*mt + fg*4 + r;
                const float val = (i >= j) ? g[mt][nt][r] * sm.douti[i] : 0.0f;
                sm.M[i][j] = (__bf16)val;
            }
        }
    __syncthreads();   // S3: M fully written

    // ---- phase 2: ad = M' @ Xs (Xs frags from global) ----
    f32x4 ad[2][2] = {};
    #pragma unroll
    for (int ks = 0; ks < 2; ++ks) {
        const int k0 = ks*32 + fg*8;
        const bf16x8 m0 = *reinterpret_cast<const bf16x8*>(&sm.M[wm      + fr][k0]);
        const bf16x8 m1 = *reinterpret_cast<const bf16x8*>(&sm.M[wm + 16 + fr][k0]);
        ad[0][0] = mfma16(m0, xsf[ks][0], ad[0][0]);
        ad[0][1] = mfma16(m0, xsf[ks][1], ad[0][1]);
        ad[1][0] = mfma16(m1, xsf[ks][0], ad[1][0]);
        ad[1][1] = mfma16(m1, xsf[ks][1], ad[1][1]);
    }
    __syncthreads();   // S4: all Ct/BM/M reads done -> safe to overlay sY

    float (*sY)[68] = reinterpret_cast<float(*)[68]>(&sm);   // 17408 B over Ct+BM
    #pragma unroll
    for (int mt = 0; mt < 2; ++mt)
        #pragma unroll
        for (int nt = 0; nt < 2; ++nt) {
            const int pcol = wn + 16*nt + fr;
            #pragma unroll
            for (int r = 0; r < 4; ++r) {
                const int i = wm + 16*mt + fg*4 + r;
                sY[i][pcol] = ad[mt][nt][r] + sm.dout[i]*ao[mt][nt][r];
            }
        }
    __syncthreads();   // S5

    #pragma unroll
    for (int it = 0; it < 4; ++it) {
        const int flat = tid + 256*it;
        const int row = flat >> 4;
        const int q4  = (flat & 15)*4;
        const float4 v = *reinterpret_cast<const float4*>(&sY[row][q4]);
        *reinterpret_cast<float4*>(&Yg[((tbase + row)*16 + hh)*(size_t)64 + q4]) = v;
    }
}

extern "C" void kernel_launch(void* const* d_in, const int* in_sizes, int n_in,
                              void* d_out, int out_size, void* d_ws, size_t ws_size,
                              hipStream_t stream) {
    const float* X  = (const float*)d_in[0];
    const float* I  = (const float*)d_in[1];
    const float* A  = (const float*)d_in[2];
    const float* Bp = (const float*)d_in[3];
    const float* Cp = (const float*)d_in[4];
    float* Y = (float*)d_out;
    __bf16* states = (__bf16*)d_ws;                                   // 67,108,864 B
    float*  cs63   = (float*)((char*)d_ws + (size_t)67108864);        //     32,768 B
    __bf16* xts    = (__bf16*)((char*)d_ws + (size_t)67141632);       // 67,108,864 B

    kA_chunkstate<<<dim3(16,64,8), 256, 0, stream>>>(X, A, Bp, states, xts, cs63);
    kB_scan      <<<dim3(2,16,8),  256, 0, stream>>>(I, states, cs63);
    kC_output    <<<dim3(16,64,8), 256, 0, stream>>>(A, Bp, Cp, states, xts, Y);
}

// Round 6
// 211.352 us; speedup vs baseline: 1.1674x; 1.0643x over previous
//
#include <hip/hip_runtime.h>

// Mamba-2 SSD chunked scan, 3-phase MFMA decomposition (round 6).
// Phase A: chunk_state = Xs^T B (MFMA), Xs = X*exp(cs63-cs).
// Phase B: prefix scan over chunks (in-place, prefetched).
// Phase C: G=C B^T -> M = G*e^{cs_i}*e^{-cs_j} masked; Y = M@X + diag(e^{cs})*(C@Sp^T),
//          Sp fragments read DIRECTLY from global bf16 (no LDS staging).
// Round-6: xts export dropped (r5: net loss, kA +40us for kC -2us); cc-fastest
// grid (r3 conditions); kC keeps spf-direct + 3-buffer LDS (28.2KB, 5 blk/CU);
// raw X^T staging in kC (no scan dependency on the staging path).

typedef __bf16 bf16x4 __attribute__((ext_vector_type(4)));
typedef __bf16 bf16x8 __attribute__((ext_vector_type(8)));
typedef float  f32x4  __attribute__((ext_vector_type(4)));

constexpr int LDT = 72;   // padded LDS row stride (bf16), 144 B (16B-aligned rows)

__device__ __forceinline__ f32x4 mfma16(bf16x8 a, bf16x8 b, f32x4 c) {
    return __builtin_amdgcn_mfma_f32_16x16x32_bf16(a, b, c, 0, 0, 0);
}

// ---------------- Phase A: chunk states ----------------
__global__ __launch_bounds__(256, 4)
void kA_chunkstate(const float* __restrict__ Xg, const float* __restrict__ Ag,
                   const float* __restrict__ Bg, __bf16* __restrict__ states,
                   float* __restrict__ cs63)
{
    const int cc = blockIdx.x, hh = blockIdx.y, bb = blockIdx.z;
    const int tid = threadIdx.x;
    __shared__ __bf16 sXt[64][LDT];   // Xs^T [p][l]  (later: out staging [p][n])
    __shared__ __bf16 sBt[64][LDT];   // B^T [n][l]
    __shared__ float  sds[64];
    const size_t tbase = (size_t)bb*4096 + (size_t)cc*64;
    const size_t slab  = (((size_t)bb*16 + hh)*64 + cc)*(size_t)4096;

    // ---- issue all global loads first ----
    const int lt0 = (tid >> 4) * 4;   // l block
    const int cq0 = (tid & 15) * 4;   // p/n col block
    float xr[4][4], br[4][4];
    #pragma unroll
    for (int j = 0; j < 4; ++j) {
        const size_t go = ((tbase + lt0 + j)*16 + hh)*(size_t)64 + cq0;
        *reinterpret_cast<float4*>(xr[j]) = *reinterpret_cast<const float4*>(&Xg[go]);
        *reinterpret_cast<float4*>(br[j]) = *reinterpret_cast<const float4*>(&Bg[go]);
    }
    // ---- A scan (wave 0) ----
    if (tid < 64) {
        float v = Ag[(tbase + tid)*16 + hh];
        #pragma unroll
        for (int o = 1; o < 64; o <<= 1) { float u = __shfl_up(v, o, 64); if (tid >= o) v += u; }
        const float last = __shfl(v, 63, 64);
        sds[tid] = expf(last - v);
        if (tid == 63) cs63[((size_t)bb*16 + hh)*64 + cc] = v;
    }
    // ---- B^T stage (4x4 reg transpose, no scan dependency) ----
    #pragma unroll
    for (int q = 0; q < 4; ++q)
        *reinterpret_cast<bf16x4*>(&sBt[cq0+q][lt0]) =
            (bf16x4){(__bf16)br[0][q], (__bf16)br[1][q],
                     (__bf16)br[2][q], (__bf16)br[3][q]};
    __syncthreads();   // S0: sds ready
    const float d0 = sds[lt0], d1 = sds[lt0+1], d2 = sds[lt0+2], d3 = sds[lt0+3];
    #pragma unroll
    for (int q = 0; q < 4; ++q)
        *reinterpret_cast<bf16x4*>(&sXt[cq0+q][lt0]) =
            (bf16x4){(__bf16)(xr[0][q]*d0), (__bf16)(xr[1][q]*d1),
                     (__bf16)(xr[2][q]*d2), (__bf16)(xr[3][q]*d3)};
    __syncthreads();   // S1: stage visible

    const int lane = tid & 63;
    const int wm = ((tid >> 7) & 1) * 32;
    const int wn = ((tid >> 6) & 1) * 32;
    const int fr = lane & 15, fg = lane >> 4;

    f32x4 acc[2][2] = {};
    #pragma unroll
    for (int ks = 0; ks < 2; ++ks) {
        const int k0 = ks*32 + fg*8;
        const bf16x8 a0 = *reinterpret_cast<const bf16x8*>(&sXt[wm      + fr][k0]);
        const bf16x8 a1 = *reinterpret_cast<const bf16x8*>(&sXt[wm + 16 + fr][k0]);
        const bf16x8 b0 = *reinterpret_cast<const bf16x8*>(&sBt[wn      + fr][k0]);
        const bf16x8 b1 = *reinterpret_cast<const bf16x8*>(&sBt[wn + 16 + fr][k0]);
        acc[0][0] = mfma16(a0, b0, acc[0][0]);
        acc[0][1] = mfma16(a0, b1, acc[0][1]);
        acc[1][0] = mfma16(a1, b0, acc[1][0]);
        acc[1][1] = mfma16(a1, b1, acc[1][1]);
    }
    __syncthreads();  // S2: all sXt/sBt reads done; overlay sXt with output

    __bf16 (*sOut)[LDT] = sXt;
    #pragma unroll
    for (int mt = 0; mt < 2; ++mt)
        #pragma unroll
        for (int nt = 0; nt < 2; ++nt)
            #pragma unroll
            for (int r = 0; r < 4; ++r)
                sOut[wm + 16*mt + fg*4 + r][wn + 16*nt + fr] = (__bf16)acc[mt][nt][r];
    __syncthreads();  // S3: sOut visible

    __bf16* dst = states + slab;
    #pragma unroll
    for (int it = 0; it < 2; ++it) {
        const int flat = tid + 256*it;
        const int p = flat >> 3, n8 = (flat & 7)*8;
        *reinterpret_cast<bf16x8*>(&dst[p*64 + n8]) =
            *reinterpret_cast<const bf16x8*>(&sOut[p][n8]);
    }
}

// ---------------- Phase B: prefix scan over chunks (in-place) ----------------
__global__ __launch_bounds__(256)
void kB_scan(const float* __restrict__ Ig, __bf16* __restrict__ states,
             const float* __restrict__ cs63)
{
    const int ph = blockIdx.x, hh = blockIdx.y, bb = blockIdx.z;
    const int tid = threadIdx.x;
    const int p  = ph*32 + (tid >> 3);
    const int n8 = (tid & 7) * 8;
    const float* ip = &Ig[(((size_t)bb*16 + hh)*64 + p)*(size_t)64 + n8];
    const float4 i0 = *reinterpret_cast<const float4*>(ip);
    const float4 i1 = *reinterpret_cast<const float4*>(ip + 4);
    float r[8] = {i0.x, i0.y, i0.z, i0.w, i1.x, i1.y, i1.z, i1.w};
    const float* csp = &cs63[((size_t)bb*16 + hh)*64];
    __bf16* sp = states + ((size_t)bb*16 + hh)*64*4096 + p*64 + n8;

    bf16x8 nxt = *reinterpret_cast<const bf16x8*>(sp);
    float dnxt = expf(csp[0]);
    for (int c = 0; c < 64; ++c) {
        const bf16x8 cur = nxt;
        const float d = dnxt;
        if (c < 63) {
            nxt = *reinterpret_cast<const bf16x8*>(sp + (size_t)(c + 1)*4096);
            dnxt = expf(csp[c + 1]);
        }
        bf16x8 pr;
        #pragma unroll
        for (int j = 0; j < 8; ++j) pr[j] = (__bf16)r[j];
        *reinterpret_cast<bf16x8*>(sp + (size_t)c*4096) = pr;   // prefix[c]
        #pragma unroll
        for (int j = 0; j < 8; ++j) r[j] = fmaf(d, r[j], (float)cur[j]);
    }
}

// ---------------- Phase C: outputs ----------------
struct SMemC {
    __bf16 Ct[64][LDT];   // C [l][n]        } overlaid by sY[64][68] f32 after
    __bf16 BM[64][LDT];   // B [l][n] -> M   } phase-2 reads complete
    __bf16 Xt[64][LDT];   // X^T [p][l] (raw)
    float  dout[64];      // e^{cs_i}
    float  din[64];       // e^{-cs_j}
};

__global__ __launch_bounds__(256, 5)
void kC_output(const float* __restrict__ Xg, const float* __restrict__ Ag,
               const float* __restrict__ Bg, const float* __restrict__ Cg,
               const __bf16* __restrict__ states, float* __restrict__ Yg)
{
    const int cc = blockIdx.x, hh = blockIdx.y, bb = blockIdx.z;
    const int tid = threadIdx.x;
    __shared__ __align__(16) SMemC sm;
    const size_t tbase = (size_t)bb*4096 + (size_t)cc*64;
    const size_t slab  = (((size_t)bb*16 + hh)*64 + cc)*(size_t)4096;

    const int r0 = tid >> 4, c4 = (tid & 15) * 4;
    const int lt0 = (tid >> 4)*4, cq0 = (tid & 15) * 4;
    const int lane = tid & 63;
    const int wm = ((tid >> 7) & 1) * 32;
    const int wn = ((tid >> 6) & 1) * 32;
    const int fr = lane & 15, fg = lane >> 4;

    // ---- issue ALL global loads upfront ----
    float cv[4][4], bv[4][4], xr[4][4];
    #pragma unroll
    for (int it = 0; it < 4; ++it) {
        const size_t go = ((tbase + r0 + 16*it)*16 + hh)*(size_t)64 + c4;
        *reinterpret_cast<float4*>(cv[it]) = *reinterpret_cast<const float4*>(&Cg[go]);
        *reinterpret_cast<float4*>(bv[it]) = *reinterpret_cast<const float4*>(&Bg[go]);
    }
    #pragma unroll
    for (int j = 0; j < 4; ++j) {
        const size_t go = ((tbase + lt0 + j)*16 + hh)*(size_t)64 + cq0;
        *reinterpret_cast<float4*>(xr[j]) = *reinterpret_cast<const float4*>(&Xg[go]);
    }
    const __bf16* stp = states + slab;
    bf16x8 spf[2][2];
    #pragma unroll
    for (int ks = 0; ks < 2; ++ks) {
        const int k0 = ks*32 + fg*8;
        spf[ks][0] = *reinterpret_cast<const bf16x8*>(&stp[(wn      + fr)*64 + k0]);
        spf[ks][1] = *reinterpret_cast<const bf16x8*>(&stp[(wn + 16 + fr)*64 + k0]);
    }

    // ---- A scan (wave 0) -> decay tables ----
    if (tid < 64) {
        float v = Ag[(tbase + tid)*16 + hh];
        #pragma unroll
        for (int o = 1; o < 64; o <<= 1) { float u = __shfl_up(v, o, 64); if (tid >= o) v += u; }
        sm.dout[tid] = expf(v);
        sm.din[tid]  = expf(-v);
    }

    // ---- stage C, B (flat), X^T (4x4 reg transpose, raw) ----
    #pragma unroll
    for (int it = 0; it < 4; ++it) {
        const int l = r0 + 16*it;
        *reinterpret_cast<bf16x4*>(&sm.Ct[l][c4]) =
            (bf16x4){(__bf16)cv[it][0], (__bf16)cv[it][1],
                     (__bf16)cv[it][2], (__bf16)cv[it][3]};
        *reinterpret_cast<bf16x4*>(&sm.BM[l][c4]) =
            (bf16x4){(__bf16)bv[it][0], (__bf16)bv[it][1],
                     (__bf16)bv[it][2], (__bf16)bv[it][3]};
    }
    #pragma unroll
    for (int q = 0; q < 4; ++q)
        *reinterpret_cast<bf16x4*>(&sm.Xt[cq0+q][lt0]) =
            (bf16x4){(__bf16)xr[0][q], (__bf16)xr[1][q],
                     (__bf16)xr[2][q], (__bf16)xr[3][q]};
    __syncthreads();   // S1: stage + tables visible

    // ---- phase 1: G = C B^T  and  ao = C @ Sp^T (Sp frags from global) ----
    f32x4 g[2][2] = {}, ao[2][2] = {};
    #pragma unroll
    for (int ks = 0; ks < 2; ++ks) {
        const int k0 = ks*32 + fg*8;
        const bf16x8 a0 = *reinterpret_cast<const bf16x8*>(&sm.Ct[wm      + fr][k0]);
        const bf16x8 a1 = *reinterpret_cast<const bf16x8*>(&sm.Ct[wm + 16 + fr][k0]);
        const bf16x8 b0 = *reinterpret_cast<const bf16x8*>(&sm.BM[wn      + fr][k0]);
        const bf16x8 b1 = *reinterpret_cast<const bf16x8*>(&sm.BM[wn + 16 + fr][k0]);
        g[0][0] = mfma16(a0, b0, g[0][0]);
        g[0][1] = mfma16(a0, b1, g[0][1]);
        g[1][0] = mfma16(a1, b0, g[1][0]);
        g[1][1] = mfma16(a1, b1, g[1][1]);
        ao[0][0] = mfma16(a0, spf[ks][0], ao[0][0]);
        ao[0][1] = mfma16(a0, spf[ks][1], ao[0][1]);
        ao[1][0] = mfma16(a1, spf[ks][0], ao[1][0]);
        ao[1][1] = mfma16(a1, spf[ks][1], ao[1][1]);
    }
    __syncthreads();   // S2: all BM(B) reads done

    // ---- M = G * e^{cs_i} * e^{-cs_j}, masked -> overlay onto BM ----
    #pragma unroll
    for (int mt = 0; mt < 2; ++mt)
        #pragma unroll
        for (int nt = 0; nt < 2; ++nt) {
            const int j = wn + 16*nt + fr;
            const float dj = sm.din[j];
            #pragma unroll
            for (int r = 0; r < 4; ++r) {
                const int i = wm + 16*mt + fg*4 + r;
                const float val = (i >= j) ? g[mt][nt][r] * sm.dout[i] * dj : 0.0f;
                sm.BM[i][j] = (__bf16)val;
            }
        }
    __syncthreads();   // S3: M fully written

    // ---- phase 2: ad = M @ X (Xt frags from LDS) ----
    f32x4 ad[2][2] = {};
    #pragma unroll
    for (int ks = 0; ks < 2; ++ks) {
        const int k0 = ks*32 + fg*8;
        const bf16x8 m0 = *reinterpret_cast<const bf16x8*>(&sm.BM[wm      + fr][k0]);
        const bf16x8 m1 = *reinterpret_cast<const bf16x8*>(&sm.BM[wm + 16 + fr][k0]);
        const bf16x8 x0 = *reinterpret_cast<const bf16x8*>(&sm.Xt[wn      + fr][k0]);
        const bf16x8 x1 = *reinterpret_cast<const bf16x8*>(&sm.Xt[wn + 16 + fr][k0]);
        ad[0][0] = mfma16(m0, x0, ad[0][0]);
        ad[0][1] = mfma16(m0, x1, ad[0][1]);
        ad[1][0] = mfma16(m1, x0, ad[1][0]);
        ad[1][1] = mfma16(m1, x1, ad[1][1]);
    }
    __syncthreads();   // S4: all Ct/BM/Xt reads done -> safe to overlay sY

    float (*sY)[68] = reinterpret_cast<float(*)[68]>(&sm);   // 17408 B over Ct+BM
    #pragma unroll
    for (int mt = 0; mt < 2; ++mt)
        #pragma unroll
        for (int nt = 0; nt < 2; ++nt) {
            const int pcol = wn + 16*nt + fr;
            #pragma unroll
            for (int r = 0; r < 4; ++r) {
                const int i = wm + 16*mt + fg*4 + r;
                sY[i][pcol] = ad[mt][nt][r] + sm.dout[i]*ao[mt][nt][r];
            }
        }
    __syncthreads();   // S5

    #pragma unroll
    for (int it = 0; it < 4; ++it) {
        const int flat = tid + 256*it;
        const int row = flat >> 4;
        const int q4  = (flat & 15)*4;
        const float4 v = *reinterpret_cast<const float4*>(&sY[row][q4]);
        *reinterpret_cast<float4*>(&Yg[((tbase + row)*16 + hh)*(size_t)64 + q4]) = v;
    }
}

extern "C" void kernel_launch(void* const* d_in, const int* in_sizes, int n_in,
                              void* d_out, int out_size, void* d_ws, size_t ws_size,
                              hipStream_t stream) {
    const float* X  = (const float*)d_in[0];
    const float* I  = (const float*)d_in[1];
    const float* A  = (const float*)d_in[2];
    const float* Bp = (const float*)d_in[3];
    const float* Cp = (const float*)d_in[4];
    float* Y = (float*)d_out;
    __bf16* states = (__bf16*)d_ws;                                   // 67,108,864 B
    float*  cs63   = (float*)((char*)d_ws + (size_t)67108864);        //     32,768 B

    kA_chunkstate<<<dim3(64,16,8), 256, 0, stream>>>(X, A, Bp, states, cs63);
    kB_scan      <<<dim3(2,16,8),  256, 0, stream>>>(I, states, cs63);
    kC_output    <<<dim3(64,16,8), 256, 0, stream>>>(X, A, Bp, Cp, states, Y);
}